// Round 5
// baseline (5773.098 us; speedup 1.0000x reference)
//
#include <hip/hip_runtime.h>
#include <stdint.h>
#include <stddef.h>

typedef uint16_t u16_t;
typedef uint32_t u32_t;
typedef short s16x8 __attribute__((ext_vector_type(8)));
typedef uint16_t u16x4v __attribute__((ext_vector_type(4)));
typedef uint16_t u16x8v __attribute__((ext_vector_type(8)));
typedef float f32x4 __attribute__((ext_vector_type(4)));

#define DEV static __device__ __forceinline__

DEV u16_t f2bf(float f) {
  u32_t u = __float_as_uint(f);
  u += 0x7fffu + ((u >> 16) & 1u);   // round-to-nearest-even
  return (u16_t)(u >> 16);
}
DEV float sig_(float x) { return 1.f / (1.f + __expf(-x)); }
DEV float th_(float x) {
  x = fminf(15.f, fmaxf(-15.f, x));
  float e = __expf(2.f * x);
  return (e - 1.f) / (e + 1.f);
}

// =================== setup kernels ===================

// Permuted+concatenated bf16 weights: dest row p = g*64 + q*16 + j
// <- original gate row q*HH + (p>>6)*16 + (p&15); row content = [wih | whh].
__global__ void k_buildWC(const float* __restrict__ wih, const float* __restrict__ whh,
                          const float* __restrict__ bih, const float* __restrict__ bhh,
                          u16_t* __restrict__ WC, float* __restrict__ bs, int HH)
{
  const int K = HH * 2;
  const int nk8 = K >> 3;
  const long total = (long)HH * 4 * nk8;
  long idx = (long)blockIdx.x * blockDim.x + threadIdx.x;
  if (idx >= total) return;
  int p = (int)(idx / nk8);
  int k = (int)(idx - (long)p * nk8) << 3;
  int q = (p >> 4) & 3;
  int orig = q * HH + ((p >> 6) << 4) + (p & 15);
  const float* s = (k < HH) ? (wih + (size_t)orig * HH + k)
                            : (whh + (size_t)orig * HH + (k - HH));
  f32x4 a = *(const f32x4*)s;
  f32x4 b = *(const f32x4*)(s + 4);
  u16x8v o;
  o[0]=f2bf(a[0]); o[1]=f2bf(a[1]); o[2]=f2bf(a[2]); o[3]=f2bf(a[3]);
  o[4]=f2bf(b[0]); o[5]=f2bf(b[1]); o[6]=f2bf(b[2]); o[7]=f2bf(b[3]);
  *(u16x8v*)(WC + (size_t)p * K + k) = o;
  if (k == 0) bs[p] = bih[orig] + bhh[orig];
}

// init slab 0 of XIN/H1/H2 (bf16)
__global__ void k_init(const float* __restrict__ h0f, const float* __restrict__ h0b,
                       const float* __restrict__ h01, const float* __restrict__ h02,
                       u16_t* __restrict__ XIN0, u16_t* __restrict__ H1i, u16_t* __restrict__ H2i)
{
  int i = blockIdx.x * 256 + threadIdx.x;
  if (i >= 64 * 1024) return;
  int b = i >> 10, d = i & 1023;
  XIN0[i] = f2bf(d < 512 ? h0f[b * 512 + d] : h0b[b * 512 + (d - 512)]);
  H1i[i] = f2bf(h01[i]);
  H2i[i] = f2bf(h02[i]);
}

// embedding gather, faithful .view(S,B,H) remap + padding_idx=0
__global__ void k_emb(const int* __restrict__ x, const float* __restrict__ emb,
                      u16_t* __restrict__ Xemb)
{
  int idx = blockIdx.x * 256 + threadIdx.x;
  if (idx >= 524288) return;
  int sb = idx >> 6;
  int h0 = (idx & 63) << 3;
  int token = x[(sb >> 7) * 128 + (sb & 127)];
  u16x8v o = {0,0,0,0,0,0,0,0};
  if (token != 0) {
    const float* e = emb + (size_t)token * 512 + h0;
    f32x4 a = *(const f32x4*)e;
    f32x4 b = *(const f32x4*)(e + 4);
    o[0]=f2bf(a[0]); o[1]=f2bf(a[1]); o[2]=f2bf(a[2]); o[3]=f2bf(a[3]);
    o[4]=f2bf(b[0]); o[5]=f2bf(b[1]); o[6]=f2bf(b[2]); o[7]=f2bf(b[3]);
  }
  *(u16x8v*)(Xemb + (size_t)sb * 512 + h0) = o;
}

// =================== GEMM helpers ===================
// Stage A chunk [64 x 512 bf16] into LDS with XOR swizzle (G4: kills the
// stride-1024B 16-way bank conflict on ds_read_b128). W = waves per WG.
template<int W>
DEV void stage_chunkT(u16_t* smem, const u16_t* src, int ld, int wave, int lane)
{
#pragma unroll
  for (int j = 0; j < 64 / W; ++j) {
    int r = j * W + wave;
    s16x8 v = *(const s16x8*)(src + (size_t)r * ld + lane * 8);
    *(s16x8*)((char*)smem + r * 1024 + ((lane * 16) ^ ((r & 7) << 4))) = v;
  }
}

DEV s16x8 ld_afrag(const u16_t* smem, int m, int s, int lane)
{
  int r = m * 16 + (lane & 15);
  int off = (s * 64 + ((lane >> 4) << 4)) ^ ((r & 7) << 4);
  return *(const s16x8*)((const char*)smem + r * 1024 + off);
}

// one 512-K chunk via LDS staging, streamed (L2-resident) weights (off-chain)
DEV void chunk_stream(u16_t* smem, f32x4 acc[4], const u16_t* a, int ld,
                      const u16_t* wptr, int wave, int lane)
{
  __syncthreads();
  stage_chunkT<8>(smem, a, ld, wave, lane);
  __syncthreads();
#pragma unroll
  for (int s = 0; s < 16; ++s) {
    s16x8 bf = *(const s16x8*)(wptr + s * 32);
#pragma unroll
    for (int m = 0; m < 4; ++m) {
      s16x8 af = ld_afrag(smem, m, s, lane);
      acc[m] = __builtin_amdgcn_mfma_f32_16x16x32_bf16(af, bf, acc[m], 0, 0, 0);
    }
  }
}

// one 512-K chunk, DIRECT global->MFMA A-fragments, register weights
// (critical path: no LDS, no barriers; redundancy absorbed by local L1/L2)
DEV void dchunk(f32x4 acc[4], const u16_t* a, int ld, const s16x8 wr[16], int lane)
{
#pragma unroll
  for (int s = 0; s < 16; ++s) {
#pragma unroll
    for (int m = 0; m < 4; ++m) {
      s16x8 af = *(const s16x8*)(a + (size_t)(m * 16 + (lane & 15)) * ld
                                 + s * 32 + ((lane >> 4) << 3));
      acc[m] = __builtin_amdgcn_mfma_f32_16x16x32_bf16(af, wr[s], acc[m], 0, 0, 0);
    }
  }
}

// wave's [64 x 16] tile -> smem exchange ex[wave][row][col]
DEV void acc_to_ex(float* ex, const f32x4 acc[4], int wave, int lane)
{
#pragma unroll
  for (int m = 0; m < 4; ++m)
#pragma unroll
    for (int r = 0; r < 4; ++r)
      ex[wave * 1024 + (m * 16 + ((lane >> 4) << 2) + r) * 16 + (lane & 15)] = acc[m][r];
}

// =================== fenceless flag sync ===================
// Data published with relaxed agent-scope atomic stores (commit at the
// coherence point / L3). __syncthreads drains vmcnt before the flag store.
// NO agent fences anywhere -> no L2 invalidates, weights stay L2-resident.
DEV void ast8(void* p, const void* v)
{
  unsigned long long u; __builtin_memcpy(&u, v, 8);
  __hip_atomic_store((unsigned long long*)p, u, __ATOMIC_RELAXED, __HIP_MEMORY_SCOPE_AGENT);
}

DEV void wait_flags(u32_t* f, int n, int tid)
{
  if (tid < 64) {
    int guard = 0;
    for (;;) {
      u32_t v = (tid < n) ? __hip_atomic_load(f + tid, __ATOMIC_RELAXED, __HIP_MEMORY_SCOPE_AGENT) : 1u;
      if (__all(v != 0)) break;
      if (++guard > (1 << 22)) break;   // safety: never hang forever
      __builtin_amdgcn_s_sleep(1);      // throttle poll traffic off the fabric
    }
  }
  __builtin_amdgcn_fence(__ATOMIC_ACQUIRE, "workgroup");  // compiler ordering only
  __syncthreads();
}

DEV void set_flag(u32_t* f, int tid)
{
  __syncthreads();   // s_waitcnt vmcnt(0) for every wave before s_barrier
  if (tid == 0) {
    __builtin_amdgcn_fence(__ATOMIC_RELEASE, "workgroup");  // compiler ordering only
    __hip_atomic_store(f, 1u, __ATOMIC_RELAXED, __HIP_MEMORY_SCOPE_AGENT);
  }
}

// Pin fragments in VGPRs: opaque producer the compiler cannot sink loads past.
#define PIN16(W) { _Pragma("unroll") for (int _s = 0; _s < 16; ++_s) \
                     asm volatile("" : "+v"((W)[_s])); }
#define PIN32(W) { _Pragma("unroll") for (int _s = 0; _s < 32; ++_s) \
                     asm volatile("" : "+v"((W)[_s])); }

// =================== persistent RNN kernel ===================
// 96 WGs x 512 threads (8 waves): wg 0..31 cells (fwd 0..15, bwd 16..31),
// 32..63 layer1 (G=wg-32), 64..95 layer2 (G=wg-64). Each WG owns 128 gate
// cols = 32 h-dims. All cross-WG buffers are per-step fresh slabs.
// Chain restructure: L1's GEMM depends only on FLA[u-1] (h1 prev); only its
// ACTIVATION needs c2 (single FLB flag) -> L1(u+1) GEMM runs parallel to
// L2(u)'s late segment.
struct RP {
  const u16_t *WCf, *WCb, *WC1, *WC2;
  const float *bsf, *bsb, *bs1, *bs2;
  const u16_t *Xemb;
  u16_t *XIN, *H1, *H2;     // [129][64][1024] bf16 slabs
  float *C2;                // [129][64][1024] f32 slabs (slab u+1 = c2 after step u)
  u32_t *FLC, *FLA, *FLB;   // [128][32]
  const float *c0f, *c0b, *c02;
};

__global__ __launch_bounds__(512, 2) void k_rnn(RP P)
{
  __shared__ u16_t smem[32768];  // 64 KB staging, reused as f32 exchange [8][64][16]
  const int tid = threadIdx.x;
  const int wave = tid >> 6, lane = tid & 63;
  const int wg = blockIdx.x;
  // activation thread map: 4 outputs per thread
  const int b  = tid >> 3;          // batch 0..63
  const int d0 = (tid & 7) << 2;    // local h-dim base 0..28
  const int gl = d0 >> 4;           // 16-block within the 32 dims
  const int jj = d0 & 15;
  const f32x4 vzero = {0.f, 0.f, 0.f, 0.f};

  if (wg < 32) {
    // ---------------- fwd/bwd cells ----------------
    const bool cfwd = wg < 16;
    const int G = cfwd ? wg : wg - 16;          // 0..15 within direction
    const u16_t* WCc = cfwd ? P.WCf : P.WCb;
    const float* bsc = cfwd ? P.bsf : P.bsb;
    const float* c0 = cfwd ? P.c0f : P.c0b;
    float c_cell[4];
#pragma unroll
    for (int i = 0; i < 4; ++i) c_cell[i] = c0[b * 512 + G * 32 + d0 + i];
    const u16_t* wrow = WCc + (size_t)(G * 128 + wave * 16 + (lane & 15)) * 1024
                        + ((lane >> 4) << 3);
    s16x8 wL[16];                   // late half K 512..1023 (own-h side) in regs
#pragma unroll
    for (int s = 0; s < 16; ++s) wL[s] = *(const s16x8*)(wrow + 512 + s * 32);
    PIN16(wL);

    for (int t = 0; t < 128; ++t) {
      f32x4 acc[4] = {vzero, vzero, vzero, vzero};
      int trow = cfwd ? t : 127 - t;
      // early: embedding chunk (always available), streamed weights
      chunk_stream(smem, acc, P.Xemb + (size_t)trow * 32768, 512, wrow, wave, lane);
      // late: own-direction h(t-1), direct loads
      if (t > 0) wait_flags(P.FLC + (t - 1) * 32 + (cfwd ? 0 : 16), 16, tid);
      dchunk(acc, P.XIN + (size_t)t * 65536 + (cfwd ? 0 : 512), 1024, wL, lane);
      __syncthreads();
      float* ex = (float*)smem;
      acc_to_ex(ex, acc, wave, lane);
      __syncthreads();
      u16x4v hv;
#pragma unroll
      for (int i = 0; i < 4; ++i) {
        int j = jj + i;
        float gq[4];
#pragma unroll
        for (int q = 0; q < 4; ++q)
          gq[q] = ex[(gl * 4 + q) * 1024 + b * 16 + j] + bsc[G * 128 + gl * 64 + q * 16 + j];
        float c = sig_(gq[1]) * c_cell[i] + sig_(gq[0]) * th_(gq[2]);
        c_cell[i] = c;
        hv[i] = f2bf(sig_(gq[3]) * th_(c));
      }
      ast8(P.XIN + (size_t)(t + 1) * 65536 + b * 1024 + (cfwd ? 0 : 512) + G * 32 + d0, &hv);
      set_flag(P.FLC + t * 32 + wg, tid);
    }
  } else if (wg < 64) {
    // ---------------- stacked layer 1 ----------------
    const int G = wg - 32;
    const u16_t* wrow = P.WC1 + (size_t)(G * 128 + wave * 16 + (lane & 15)) * 2048
                        + ((lane >> 4) << 3);
    s16x8 wL[32];                   // late: h1-prev side K 1024..2047 in regs
#pragma unroll
    for (int s = 0; s < 32; ++s) wL[s] = *(const s16x8*)(wrow + 1024 + s * 32);
    PIN32(wL);

    for (int u = 0; u < 128; ++u) {
      f32x4 acc[4] = {vzero, vzero, vzero, vzero};
      // early: xin_u (cells run far ahead), streamed weights, off-chain
      wait_flags(P.FLC + u * 32, 32, tid);
      const u16_t* xin = P.XIN + (size_t)(u + 1) * 65536;
      chunk_stream(smem, acc, xin, 1024, wrow, wave, lane);
      chunk_stream(smem, acc, xin + 512, 1024, wrow + 512, wave, lane);
      // late GEMM: h1(u-1) -- needs only FLA[u-1] (NOT FLB) -> runs in
      // parallel with L2(u-1)'s late segment. Half-waits pipelined.
      const u16_t* h1p = P.H1 + (size_t)u * 65536;
      if (u > 0) wait_flags(P.FLA + (u - 1) * 32, 16, tid);
      dchunk(acc, h1p, 1024, wL, lane);
      if (u > 0) wait_flags(P.FLA + (u - 1) * 32, 32, tid);
      dchunk(acc, h1p + 512, 1024, wL + 16, lane);
      __syncthreads();
      float* ex = (float*)smem;
      acc_to_ex(ex, acc, wave, lane);
      __syncthreads();
      // activation: needs c2(u) -- single point-to-point flag from L2(u-1)
      if (u > 0) wait_flags(P.FLB + (u - 1) * 32 + G, 1, tid);
      const float* c2p = (u == 0) ? (P.c02 + b * 1024 + G * 32 + d0)
                                  : (P.C2 + (size_t)u * 65536 + b * 1024 + G * 32 + d0);
      u16x4v hv;
#pragma unroll
      for (int i = 0; i < 4; ++i) {
        int j = jj + i;
        float gq[4];
#pragma unroll
        for (int q = 0; q < 4; ++q)
          gq[q] = ex[(gl * 4 + q) * 1024 + b * 16 + j] + P.bs1[G * 128 + gl * 64 + q * 16 + j];
        // faithful quirk: layer-1 cell consumes c2; its own c is discarded
        float c1 = sig_(gq[1]) * c2p[i] + sig_(gq[0]) * th_(gq[2]);
        hv[i] = f2bf(sig_(gq[3]) * th_(c1));
      }
      ast8(P.H1 + (size_t)(u + 1) * 65536 + b * 1024 + G * 32 + d0, &hv);
      set_flag(P.FLA + u * 32 + G, tid);
    }
  } else {
    // ---------------- stacked layer 2 ----------------
    const int G = wg - 64;
    const u16_t* wrow = P.WC2 + (size_t)(G * 128 + wave * 16 + (lane & 15)) * 2048
                        + ((lane >> 4) << 3);
    s16x8 wL[32];                   // late: h1n side K 0..1023 in regs
#pragma unroll
    for (int s = 0; s < 32; ++s) wL[s] = *(const s16x8*)(wrow + s * 32);
    PIN32(wL);
    float c2r[4];
#pragma unroll
    for (int i = 0; i < 4; ++i) c2r[i] = P.c02[b * 1024 + G * 32 + d0 + i];

    for (int u = 0; u < 128; ++u) {
      f32x4 acc[4] = {vzero, vzero, vzero, vzero};
      // early: h2(u-1) (own-layer prev outputs), streamed weights
      const u16_t* h2p = P.H2 + (size_t)u * 65536;
      if (u > 0) wait_flags(P.FLB + (u - 1) * 32, 16, tid);
      chunk_stream(smem, acc, h2p, 1024, wrow + 1024, wave, lane);
      if (u > 0) wait_flags(P.FLB + (u - 1) * 32, 32, tid);
      chunk_stream(smem, acc, h2p + 512, 1024, wrow + 1536, wave, lane);
      // late: h1n (critical hop), direct loads, half-waits pipelined
      const u16_t* h1n = P.H1 + (size_t)(u + 1) * 65536;
      wait_flags(P.FLA + u * 32, 16, tid);
      dchunk(acc, h1n, 1024, wL, lane);
      wait_flags(P.FLA + u * 32, 32, tid);
      dchunk(acc, h1n + 512, 1024, wL + 16, lane);
      __syncthreads();
      float* ex = (float*)smem;
      acc_to_ex(ex, acc, wave, lane);
      __syncthreads();
      u16x4v hv; float c2o[4];
#pragma unroll
      for (int i = 0; i < 4; ++i) {
        int j = jj + i;
        float gq[4];
#pragma unroll
        for (int q = 0; q < 4; ++q)
          gq[q] = ex[(gl * 4 + q) * 1024 + b * 16 + j] + P.bs2[G * 128 + gl * 64 + q * 16 + j];
        float c2n = sig_(gq[1]) * c2r[i] + sig_(gq[0]) * th_(gq[2]);
        c2r[i] = c2n; c2o[i] = c2n;
        hv[i] = f2bf(sig_(gq[3]) * th_(c2n));
      }
      ast8(P.H2 + (size_t)(u + 1) * 65536 + b * 1024 + G * 32 + d0, &hv);
      float* c2dst = P.C2 + (size_t)(u + 1) * 65536 + b * 1024 + G * 32 + d0;
      ast8(c2dst, &c2o[0]);
      ast8(c2dst + 2, &c2o[2]);
      set_flag(P.FLB + u * 32 + G, tid);
    }
  }
}

// =================== final linear ===================
__global__ __launch_bounds__(256, 1) void k_logits(const u16_t* __restrict__ h2,
                                                   const float* __restrict__ wlin,
                                                   const float* __restrict__ blin,
                                                   float* __restrict__ out)
{
  __shared__ u16_t smem[32768];
  const int tid = threadIdx.x, wave = tid >> 6, lane = tid & 63;
  const int n0 = blockIdx.x * 128 + wave * 32;
  const f32x4 vzero = {0.f, 0.f, 0.f, 0.f};
  f32x4 acc[2][4];
#pragma unroll
  for (int nt = 0; nt < 2; ++nt)
#pragma unroll
    for (int m = 0; m < 4; ++m) acc[nt][m] = vzero;

  for (int c = 0; c < 2; ++c) {
    __syncthreads();
    stage_chunkT<4>(smem, h2 + c * 512, 1024, wave, lane);
    __syncthreads();
#pragma unroll
    for (int s = 0; s < 16; ++s) {
#pragma unroll
      for (int nt = 0; nt < 2; ++nt) {
        const float* wp = wlin + (size_t)(n0 + nt * 16 + (lane & 15)) * 1024
                          + c * 512 + s * 32 + ((lane >> 4) << 3);
        f32x4 w0 = *(const f32x4*)wp;
        f32x4 w1 = *(const f32x4*)(wp + 4);
        s16x8 bf;
        bf[0]=(short)f2bf(w0[0]); bf[1]=(short)f2bf(w0[1]);
        bf[2]=(short)f2bf(w0[2]); bf[3]=(short)f2bf(w0[3]);
        bf[4]=(short)f2bf(w1[0]); bf[5]=(short)f2bf(w1[1]);
        bf[6]=(short)f2bf(w1[2]); bf[7]=(short)f2bf(w1[3]);
#pragma unroll
        for (int m = 0; m < 4; ++m) {
          s16x8 af = ld_afrag(smem, m, s, lane);
          acc[nt][m] = __builtin_amdgcn_mfma_f32_16x16x32_bf16(af, bf, acc[nt][m], 0, 0, 0);
        }
      }
    }
  }
#pragma unroll
  for (int nt = 0; nt < 2; ++nt) {
    int col = n0 + nt * 16 + (lane & 15);
    float bl = blin[col];
#pragma unroll
    for (int m = 0; m < 4; ++m)
#pragma unroll
      for (int r = 0; r < 4; ++r) {
        int row = m * 16 + ((lane >> 4) << 2) + r;
        out[(size_t)row * 32000 + col] = acc[nt][m][r] + bl;
      }
  }
}

// =================== host ===================
extern "C" void kernel_launch(void* const* d_in, const int* in_sizes, int n_in,
                              void* d_out, int out_size, void* d_ws, size_t ws_size,
                              hipStream_t stream)
{
  (void)in_sizes; (void)n_in; (void)out_size;
  const int*   x     = (const int*)d_in[0];
  const float* emb   = (const float*)d_in[1];
  const float* h0f   = (const float*)d_in[2];
  const float* c0f   = (const float*)d_in[3];
  const float* h0b   = (const float*)d_in[4];
  const float* c0b   = (const float*)d_in[5];
  const float* h01   = (const float*)d_in[6];
  const float* h02   = (const float*)d_in[7];
  const float* c02   = (const float*)d_in[8];
  const float* wih_f = (const float*)d_in[9];
  const float* whh_f = (const float*)d_in[10];
  const float* bih_f = (const float*)d_in[11];
  const float* bhh_f = (const float*)d_in[12];
  const float* wih_b = (const float*)d_in[13];
  const float* whh_b = (const float*)d_in[14];
  const float* bih_b = (const float*)d_in[15];
  const float* bhh_b = (const float*)d_in[16];
  const float* wih1  = (const float*)d_in[17];
  const float* whh1  = (const float*)d_in[18];
  const float* bih1  = (const float*)d_in[19];
  const float* bhh1  = (const float*)d_in[20];
  const float* wih2  = (const float*)d_in[21];
  const float* whh2  = (const float*)d_in[22];
  const float* bih2  = (const float*)d_in[23];
  const float* bhh2  = (const float*)d_in[24];
  const float* wlin  = (const float*)d_in[25];
  const float* blin  = (const float*)d_in[26];

  char* ws = (char*)d_ws;
  size_t off = 0;
  auto take = [&](size_t n) { char* p = ws + off; off += (n + 255) & ~(size_t)255; return p; };

  u16_t* WCf  = (u16_t*)take(2048UL * 1024 * 2);
  u16_t* WCb  = (u16_t*)take(2048UL * 1024 * 2);
  u16_t* WC1  = (u16_t*)take(4096UL * 2048 * 2);
  u16_t* WC2  = (u16_t*)take(4096UL * 2048 * 2);
  float* bsf  = (float*)take(2048UL * 4);
  float* bsb  = (float*)take(2048UL * 4);
  float* bs1  = (float*)take(4096UL * 4);
  float* bs2  = (float*)take(4096UL * 4);
  u16_t* Xemb = (u16_t*)take(8192UL * 512 * 2);
  u16_t* XIN  = (u16_t*)take(129UL * 65536 * 2);
  u16_t* H1   = (u16_t*)take(129UL * 65536 * 2);
  u16_t* H2   = (u16_t*)take(129UL * 65536 * 2);
  float* C2   = (float*)take(129UL * 65536 * 4);
  char* flagbase = ws + off;
  u32_t* FLC  = (u32_t*)take(128UL * 32 * 4);
  u32_t* FLA  = (u32_t*)take(128UL * 32 * 4);
  u32_t* FLB  = (u32_t*)take(128UL * 32 * 4);
  size_t flagbytes = (size_t)((ws + off) - flagbase);

  if (off > ws_size) return;  // workspace too small: fail loudly via wrong output

  hipMemsetAsync(flagbase, 0, flagbytes, stream);

  k_buildWC<<<1024, 256, 0, stream>>>(wih_f, whh_f, bih_f, bhh_f, WCf, bsf, 512);
  k_buildWC<<<1024, 256, 0, stream>>>(wih_b, whh_b, bih_b, bhh_b, WCb, bsb, 512);
  k_buildWC<<<4096, 256, 0, stream>>>(wih1, whh1, bih1, bhh1, WC1, bs1, 1024);
  k_buildWC<<<4096, 256, 0, stream>>>(wih2, whh2, bih2, bhh2, WC2, bs2, 1024);
  k_init<<<256, 256, 0, stream>>>(h0f, h0b, h01, h02, XIN, H1, H2);
  k_emb<<<2048, 256, 0, stream>>>(x, emb, Xemb);

  RP P;
  P.WCf = WCf; P.WCb = WCb; P.WC1 = WC1; P.WC2 = WC2;
  P.bsf = bsf; P.bsb = bsb; P.bs1 = bs1; P.bs2 = bs2;
  P.Xemb = Xemb; P.XIN = XIN; P.H1 = H1; P.H2 = H2; P.C2 = C2;
  P.FLC = FLC; P.FLA = FLA; P.FLB = FLB;
  P.c0f = c0f; P.c0b = c0b; P.c02 = c02;
  k_rnn<<<96, 512, 0, stream>>>(P);

  k_logits<<<250, 256, 0, stream>>>(H2 + 128UL * 65536, wlin, blin, (float*)d_out);
}

// Round 6
// 3583.775 us; speedup vs baseline: 1.6109x; 1.6109x over previous
//
#include <hip/hip_runtime.h>
#include <stdint.h>
#include <stddef.h>

typedef uint16_t u16_t;
typedef uint32_t u32_t;
typedef short s16x8 __attribute__((ext_vector_type(8)));
typedef uint16_t u16x4v __attribute__((ext_vector_type(4)));
typedef uint16_t u16x8v __attribute__((ext_vector_type(8)));
typedef float f32x4 __attribute__((ext_vector_type(4)));

#define DEV static __device__ __forceinline__

DEV u16_t f2bf(float f) {
  u32_t u = __float_as_uint(f);
  u += 0x7fffu + ((u >> 16) & 1u);   // round-to-nearest-even
  return (u16_t)(u >> 16);
}
DEV float sig_(float x) { return 1.f / (1.f + __expf(-x)); }
DEV float th_(float x) {
  x = fminf(15.f, fmaxf(-15.f, x));
  float e = __expf(2.f * x);
  return (e - 1.f) / (e + 1.f);
}

// =================== setup kernels ===================

// Permuted+concatenated bf16 weights: dest row p = g*64 + q*16 + j
// <- original gate row q*HH + (p>>6)*16 + (p&15); row content = [wih | whh].
__global__ void k_buildWC(const float* __restrict__ wih, const float* __restrict__ whh,
                          const float* __restrict__ bih, const float* __restrict__ bhh,
                          u16_t* __restrict__ WC, float* __restrict__ bs, int HH)
{
  const int K = HH * 2;
  const int nk8 = K >> 3;
  const long total = (long)HH * 4 * nk8;
  long idx = (long)blockIdx.x * blockDim.x + threadIdx.x;
  if (idx >= total) return;
  int p = (int)(idx / nk8);
  int k = (int)(idx - (long)p * nk8) << 3;
  int q = (p >> 4) & 3;
  int orig = q * HH + ((p >> 6) << 4) + (p & 15);
  const float* s = (k < HH) ? (wih + (size_t)orig * HH + k)
                            : (whh + (size_t)orig * HH + (k - HH));
  f32x4 a = *(const f32x4*)s;
  f32x4 b = *(const f32x4*)(s + 4);
  u16x8v o;
  o[0]=f2bf(a[0]); o[1]=f2bf(a[1]); o[2]=f2bf(a[2]); o[3]=f2bf(a[3]);
  o[4]=f2bf(b[0]); o[5]=f2bf(b[1]); o[6]=f2bf(b[2]); o[7]=f2bf(b[3]);
  *(u16x8v*)(WC + (size_t)p * K + k) = o;
  if (k == 0) bs[p] = bih[orig] + bhh[orig];
}

// init slab 0 of XIN/H1/H2 (bf16)
__global__ void k_init(const float* __restrict__ h0f, const float* __restrict__ h0b,
                       const float* __restrict__ h01, const float* __restrict__ h02,
                       u16_t* __restrict__ XIN0, u16_t* __restrict__ H1i, u16_t* __restrict__ H2i)
{
  int i = blockIdx.x * 256 + threadIdx.x;
  if (i >= 64 * 1024) return;
  int b = i >> 10, d = i & 1023;
  XIN0[i] = f2bf(d < 512 ? h0f[b * 512 + d] : h0b[b * 512 + (d - 512)]);
  H1i[i] = f2bf(h01[i]);
  H2i[i] = f2bf(h02[i]);
}

// embedding gather, faithful .view(S,B,H) remap + padding_idx=0
__global__ void k_emb(const int* __restrict__ x, const float* __restrict__ emb,
                      u16_t* __restrict__ Xemb)
{
  int idx = blockIdx.x * 256 + threadIdx.x;
  if (idx >= 524288) return;
  int sb = idx >> 6;
  int h0 = (idx & 63) << 3;
  int token = x[(sb >> 7) * 128 + (sb & 127)];
  u16x8v o = {0,0,0,0,0,0,0,0};
  if (token != 0) {
    const float* e = emb + (size_t)token * 512 + h0;
    f32x4 a = *(const f32x4*)e;
    f32x4 b = *(const f32x4*)(e + 4);
    o[0]=f2bf(a[0]); o[1]=f2bf(a[1]); o[2]=f2bf(a[2]); o[3]=f2bf(a[3]);
    o[4]=f2bf(b[0]); o[5]=f2bf(b[1]); o[6]=f2bf(b[2]); o[7]=f2bf(b[3]);
  }
  *(u16x8v*)(Xemb + (size_t)sb * 512 + h0) = o;
}

// =================== GEMM helpers ===================
// Stage A chunk [64 x 512 bf16] into LDS with XOR swizzle (G4: kills the
// stride-1024B 16-way bank conflict on ds_read_b128). W = waves per WG.
template<int W>
DEV void stage_chunkT(u16_t* smem, const u16_t* src, int ld, int wave, int lane)
{
#pragma unroll
  for (int j = 0; j < 64 / W; ++j) {
    int r = j * W + wave;
    s16x8 v = *(const s16x8*)(src + (size_t)r * ld + lane * 8);
    *(s16x8*)((char*)smem + r * 1024 + ((lane * 16) ^ ((r & 7) << 4))) = v;
  }
}

DEV s16x8 ld_afrag(const u16_t* smem, int m, int s, int lane)
{
  int r = m * 16 + (lane & 15);
  int off = (s * 64 + ((lane >> 4) << 4)) ^ ((r & 7) << 4);
  return *(const s16x8*)((const char*)smem + r * 1024 + off);
}

// one 512-K chunk via LDS staging, weights streamed from L2 (they pipeline
// under MFMA issue -- measured faster than register-pinning, rounds 3-5)
DEV void chunk_stream(u16_t* smem, f32x4 acc[4], const u16_t* a, int ld,
                      const u16_t* wptr, int wave, int lane)
{
  __syncthreads();
  stage_chunkT<8>(smem, a, ld, wave, lane);
  __syncthreads();
#pragma unroll
  for (int s = 0; s < 16; ++s) {
    s16x8 bf = *(const s16x8*)(wptr + s * 32);
#pragma unroll
    for (int m = 0; m < 4; ++m) {
      s16x8 af = ld_afrag(smem, m, s, lane);
      acc[m] = __builtin_amdgcn_mfma_f32_16x16x32_bf16(af, bf, acc[m], 0, 0, 0);
    }
  }
}

// wave's [64 x 16] tile -> smem exchange ex[wave][row][col]
DEV void acc_to_ex(float* ex, const f32x4 acc[4], int wave, int lane)
{
#pragma unroll
  for (int m = 0; m < 4; ++m)
#pragma unroll
    for (int r = 0; r < 4; ++r)
      ex[wave * 1024 + (m * 16 + ((lane >> 4) << 2) + r) * 16 + (lane & 15)] = acc[m][r];
}

// =================== fenceless flag sync ===================
// Data published with relaxed agent-scope atomic stores (commit at the
// coherence point / L3). __syncthreads drains vmcnt before the flag store.
// NO agent fences anywhere -> no L2 invalidates, weights stay L2-resident.
DEV void ast8(void* p, const void* v)
{
  unsigned long long u; __builtin_memcpy(&u, v, 8);
  __hip_atomic_store((unsigned long long*)p, u, __ATOMIC_RELAXED, __HIP_MEMORY_SCOPE_AGENT);
}

DEV void wait_flags(u32_t* f, int n, int tid)
{
  if (tid < 64) {
    int guard = 0;
    for (;;) {
      u32_t v = (tid < n) ? __hip_atomic_load(f + tid, __ATOMIC_RELAXED, __HIP_MEMORY_SCOPE_AGENT) : 1u;
      if (__all(v != 0)) break;
      if (++guard > (1 << 22)) break;   // safety: never hang forever
      __builtin_amdgcn_s_sleep(1);      // throttle poll traffic off the fabric
    }
  }
  __builtin_amdgcn_fence(__ATOMIC_ACQUIRE, "workgroup");  // compiler ordering only
  __syncthreads();
}

DEV void set_flag(u32_t* f, int tid)
{
  __syncthreads();   // s_waitcnt vmcnt(0) for every wave before s_barrier
  if (tid == 0) {
    __builtin_amdgcn_fence(__ATOMIC_RELEASE, "workgroup");  // compiler ordering only
    __hip_atomic_store(f, 1u, __ATOMIC_RELAXED, __HIP_MEMORY_SCOPE_AGENT);
  }
}

// =================== persistent RNN kernel ===================
// 96 WGs x 512 threads (8 waves): wg 0..31 cells (fwd 0..15, bwd 16..31),
// 32..63 layer1 (G=wg-32), 64..95 layer2 (G=wg-64). Each WG owns 128 gate
// cols = 32 h-dims. All cross-WG buffers are per-step fresh slabs.
// Chain restructure: L1's late GEMM depends only on FLA[u-1] (h1 prev);
// only its ACTIVATION needs c2(u) (single FLB flag) -> L1(u)'s GEMM runs in
// PARALLEL with L2(u-1)'s late segment. Per-step chain ~ one GEMM segment.
struct RP {
  const u16_t *WCf, *WCb, *WC1, *WC2;
  const float *bsf, *bsb, *bs1, *bs2;
  const u16_t *Xemb;
  u16_t *XIN, *H1, *H2;     // [129][64][1024] bf16 slabs
  float *C2;                // [129][64][1024] f32 slabs (slab u+1 = c2 after step u)
  u32_t *FLC, *FLA, *FLB;   // [128][32]
  const float *c0f, *c0b, *c02;
};

__global__ __launch_bounds__(512, 2) void k_rnn(RP P)
{
  __shared__ u16_t smem[32768];  // 64 KB staging, reused as f32 exchange [8][64][16]
  const int tid = threadIdx.x;
  const int wave = tid >> 6, lane = tid & 63;
  const int wg = blockIdx.x;
  // activation thread map: 4 outputs per thread
  const int b  = tid >> 3;          // batch 0..63
  const int d0 = (tid & 7) << 2;    // local h-dim base 0..28
  const int gl = d0 >> 4;           // 16-block within the 32 dims
  const int jj = d0 & 15;
  const f32x4 vzero = {0.f, 0.f, 0.f, 0.f};

  if (wg < 32) {
    // ---------------- fwd/bwd cells ----------------
    const bool cfwd = wg < 16;
    const int G = cfwd ? wg : wg - 16;          // 0..15 within direction
    const u16_t* WCc = cfwd ? P.WCf : P.WCb;
    const float* bsc = cfwd ? P.bsf : P.bsb;
    const float* c0 = cfwd ? P.c0f : P.c0b;
    float c_cell[4];
#pragma unroll
    for (int i = 0; i < 4; ++i) c_cell[i] = c0[b * 512 + G * 32 + d0 + i];
    const u16_t* wrow = WCc + (size_t)(G * 128 + wave * 16 + (lane & 15)) * 1024
                        + ((lane >> 4) << 3);

    for (int t = 0; t < 128; ++t) {
      f32x4 acc[4] = {vzero, vzero, vzero, vzero};
      int trow = cfwd ? t : 127 - t;
      // early: embedding chunk (always available)
      chunk_stream(smem, acc, P.Xemb + (size_t)trow * 32768, 512, wrow, wave, lane);
      // late: own-direction h(t-1)
      if (t > 0) wait_flags(P.FLC + (t - 1) * 32 + (cfwd ? 0 : 16), 16, tid);
      chunk_stream(smem, acc, P.XIN + (size_t)t * 65536 + (cfwd ? 0 : 512), 1024,
                   wrow + 512, wave, lane);
      __syncthreads();
      float* ex = (float*)smem;
      acc_to_ex(ex, acc, wave, lane);
      __syncthreads();
      u16x4v hv;
#pragma unroll
      for (int i = 0; i < 4; ++i) {
        int j = jj + i;
        float gq[4];
#pragma unroll
        for (int q = 0; q < 4; ++q)
          gq[q] = ex[(gl * 4 + q) * 1024 + b * 16 + j] + bsc[G * 128 + gl * 64 + q * 16 + j];
        float c = sig_(gq[1]) * c_cell[i] + sig_(gq[0]) * th_(gq[2]);
        c_cell[i] = c;
        hv[i] = f2bf(sig_(gq[3]) * th_(c));
      }
      ast8(P.XIN + (size_t)(t + 1) * 65536 + b * 1024 + (cfwd ? 0 : 512) + G * 32 + d0, &hv);
      set_flag(P.FLC + t * 32 + wg, tid);
    }
  } else if (wg < 64) {
    // ---------------- stacked layer 1 ----------------
    const int G = wg - 32;
    const u16_t* wrow = P.WC1 + (size_t)(G * 128 + wave * 16 + (lane & 15)) * 2048
                        + ((lane >> 4) << 3);

    for (int u = 0; u < 128; ++u) {
      f32x4 acc[4] = {vzero, vzero, vzero, vzero};
      // early: xin_u (cells run far ahead -> near-zero wait)
      wait_flags(P.FLC + u * 32, 32, tid);
      const u16_t* xin = P.XIN + (size_t)(u + 1) * 65536;
      chunk_stream(smem, acc, xin, 1024, wrow, wave, lane);
      chunk_stream(smem, acc, xin + 512, 1024, wrow + 512, wave, lane);
      // late GEMM: h1(u-1) -- needs only FLA[u-1] (NOT FLB[u-1]) -> runs in
      // parallel with L2(u-1)'s late segment. Half-waits pipelined w/ chunks.
      const u16_t* h1p = P.H1 + (size_t)u * 65536;
      if (u > 0) wait_flags(P.FLA + (u - 1) * 32, 16, tid);
      chunk_stream(smem, acc, h1p, 1024, wrow + 1024, wave, lane);
      if (u > 0) wait_flags(P.FLA + (u - 1) * 32, 32, tid);
      chunk_stream(smem, acc, h1p + 512, 1024, wrow + 1536, wave, lane);
      __syncthreads();
      float* ex = (float*)smem;
      acc_to_ex(ex, acc, wave, lane);
      __syncthreads();
      // activation: needs c2(u) -- single point-to-point flag from L2(u-1)
      if (u > 0) wait_flags(P.FLB + (u - 1) * 32 + G, 1, tid);
      const float* c2p = (u == 0) ? (P.c02 + b * 1024 + G * 32 + d0)
                                  : (P.C2 + (size_t)u * 65536 + b * 1024 + G * 32 + d0);
      u16x4v hv;
#pragma unroll
      for (int i = 0; i < 4; ++i) {
        int j = jj + i;
        float gq[4];
#pragma unroll
        for (int q = 0; q < 4; ++q)
          gq[q] = ex[(gl * 4 + q) * 1024 + b * 16 + j] + P.bs1[G * 128 + gl * 64 + q * 16 + j];
        // faithful quirk: layer-1 cell consumes c2; its own c is discarded
        float c1 = sig_(gq[1]) * c2p[i] + sig_(gq[0]) * th_(gq[2]);
        hv[i] = f2bf(sig_(gq[3]) * th_(c1));
      }
      ast8(P.H1 + (size_t)(u + 1) * 65536 + b * 1024 + G * 32 + d0, &hv);
      set_flag(P.FLA + u * 32 + G, tid);
    }
  } else {
    // ---------------- stacked layer 2 ----------------
    const int G = wg - 64;
    const u16_t* wrow = P.WC2 + (size_t)(G * 128 + wave * 16 + (lane & 15)) * 2048
                        + ((lane >> 4) << 3);
    float c2r[4];
#pragma unroll
    for (int i = 0; i < 4; ++i) c2r[i] = P.c02[b * 1024 + G * 32 + d0 + i];

    for (int u = 0; u < 128; ++u) {
      f32x4 acc[4] = {vzero, vzero, vzero, vzero};
      // early: h2(u-1) (own-role prev outputs; WGs roughly in lockstep)
      const u16_t* h2p = P.H2 + (size_t)u * 65536;
      if (u > 0) wait_flags(P.FLB + (u - 1) * 32, 16, tid);
      chunk_stream(smem, acc, h2p, 1024, wrow + 1024, wave, lane);
      if (u > 0) wait_flags(P.FLB + (u - 1) * 32, 32, tid);
      chunk_stream(smem, acc, h2p + 512, 1024, wrow + 1536, wave, lane);
      // late: h1n (the critical hop), half-waits pipelined with chunks
      const u16_t* h1n = P.H1 + (size_t)(u + 1) * 65536;
      wait_flags(P.FLA + u * 32, 16, tid);
      chunk_stream(smem, acc, h1n, 1024, wrow, wave, lane);
      wait_flags(P.FLA + u * 32, 32, tid);
      chunk_stream(smem, acc, h1n + 512, 1024, wrow + 512, wave, lane);
      __syncthreads();
      float* ex = (float*)smem;
      acc_to_ex(ex, acc, wave, lane);
      __syncthreads();
      u16x4v hv; float c2o[4];
#pragma unroll
      for (int i = 0; i < 4; ++i) {
        int j = jj + i;
        float gq[4];
#pragma unroll
        for (int q = 0; q < 4; ++q)
          gq[q] = ex[(gl * 4 + q) * 1024 + b * 16 + j] + P.bs2[G * 128 + gl * 64 + q * 16 + j];
        float c2n = sig_(gq[1]) * c2r[i] + sig_(gq[0]) * th_(gq[2]);
        c2r[i] = c2n; c2o[i] = c2n;
        hv[i] = f2bf(sig_(gq[3]) * th_(c2n));
      }
      ast8(P.H2 + (size_t)(u + 1) * 65536 + b * 1024 + G * 32 + d0, &hv);
      float* c2dst = P.C2 + (size_t)(u + 1) * 65536 + b * 1024 + G * 32 + d0;
      ast8(c2dst, &c2o[0]);
      ast8(c2dst + 2, &c2o[2]);
      set_flag(P.FLB + u * 32 + G, tid);
    }
  }
}

// =================== final linear ===================
__global__ __launch_bounds__(256, 1) void k_logits(const u16_t* __restrict__ h2,
                                                   const float* __restrict__ wlin,
                                                   const float* __restrict__ blin,
                                                   float* __restrict__ out)
{
  __shared__ u16_t smem[32768];
  const int tid = threadIdx.x, wave = tid >> 6, lane = tid & 63;
  const int n0 = blockIdx.x * 128 + wave * 32;
  const f32x4 vzero = {0.f, 0.f, 0.f, 0.f};
  f32x4 acc[2][4];
#pragma unroll
  for (int nt = 0; nt < 2; ++nt)
#pragma unroll
    for (int m = 0; m < 4; ++m) acc[nt][m] = vzero;

  for (int c = 0; c < 2; ++c) {
    __syncthreads();
    stage_chunkT<4>(smem, h2 + c * 512, 1024, wave, lane);
    __syncthreads();
#pragma unroll
    for (int s = 0; s < 16; ++s) {
#pragma unroll
      for (int nt = 0; nt < 2; ++nt) {
        const float* wp = wlin + (size_t)(n0 + nt * 16 + (lane & 15)) * 1024
                          + c * 512 + s * 32 + ((lane >> 4) << 3);
        f32x4 w0 = *(const f32x4*)wp;
        f32x4 w1 = *(const f32x4*)(wp + 4);
        s16x8 bf;
        bf[0]=(short)f2bf(w0[0]); bf[1]=(short)f2bf(w0[1]);
        bf[2]=(short)f2bf(w0[2]); bf[3]=(short)f2bf(w0[3]);
        bf[4]=(short)f2bf(w1[0]); bf[5]=(short)f2bf(w1[1]);
        bf[6]=(short)f2bf(w1[2]); bf[7]=(short)f2bf(w1[3]);
#pragma unroll
        for (int m = 0; m < 4; ++m) {
          s16x8 af = ld_afrag(smem, m, s, lane);
          acc[nt][m] = __builtin_amdgcn_mfma_f32_16x16x32_bf16(af, bf, acc[nt][m], 0, 0, 0);
        }
      }
    }
  }
#pragma unroll
  for (int nt = 0; nt < 2; ++nt) {
    int col = n0 + nt * 16 + (lane & 15);
    float bl = blin[col];
#pragma unroll
    for (int m = 0; m < 4; ++m)
#pragma unroll
      for (int r = 0; r < 4; ++r) {
        int row = m * 16 + ((lane >> 4) << 2) + r;
        out[(size_t)row * 32000 + col] = acc[nt][m][r] + bl;
      }
  }
}

// =================== host ===================
extern "C" void kernel_launch(void* const* d_in, const int* in_sizes, int n_in,
                              void* d_out, int out_size, void* d_ws, size_t ws_size,
                              hipStream_t stream)
{
  (void)in_sizes; (void)n_in; (void)out_size;
  const int*   x     = (const int*)d_in[0];
  const float* emb   = (const float*)d_in[1];
  const float* h0f   = (const float*)d_in[2];
  const float* c0f   = (const float*)d_in[3];
  const float* h0b   = (const float*)d_in[4];
  const float* c0b   = (const float*)d_in[5];
  const float* h01   = (const float*)d_in[6];
  const float* h02   = (const float*)d_in[7];
  const float* c02   = (const float*)d_in[8];
  const float* wih_f = (const float*)d_in[9];
  const float* whh_f = (const float*)d_in[10];
  const float* bih_f = (const float*)d_in[11];
  const float* bhh_f = (const float*)d_in[12];
  const float* wih_b = (const float*)d_in[13];
  const float* whh_b = (const float*)d_in[14];
  const float* bih_b = (const float*)d_in[15];
  const float* bhh_b = (const float*)d_in[16];
  const float* wih1  = (const float*)d_in[17];
  const float* whh1  = (const float*)d_in[18];
  const float* bih1  = (const float*)d_in[19];
  const float* bhh1  = (const float*)d_in[20];
  const float* wih2  = (const float*)d_in[21];
  const float* whh2  = (const float*)d_in[22];
  const float* bih2  = (const float*)d_in[23];
  const float* bhh2  = (const float*)d_in[24];
  const float* wlin  = (const float*)d_in[25];
  const float* blin  = (const float*)d_in[26];

  char* ws = (char*)d_ws;
  size_t off = 0;
  auto take = [&](size_t n) { char* p = ws + off; off += (n + 255) & ~(size_t)255; return p; };

  u16_t* WCf  = (u16_t*)take(2048UL * 1024 * 2);
  u16_t* WCb  = (u16_t*)take(2048UL * 1024 * 2);
  u16_t* WC1  = (u16_t*)take(4096UL * 2048 * 2);
  u16_t* WC2  = (u16_t*)take(4096UL * 2048 * 2);
  float* bsf  = (float*)take(2048UL * 4);
  float* bsb  = (float*)take(2048UL * 4);
  float* bs1  = (float*)take(4096UL * 4);
  float* bs2  = (float*)take(4096UL * 4);
  u16_t* Xemb = (u16_t*)take(8192UL * 512 * 2);
  u16_t* XIN  = (u16_t*)take(129UL * 65536 * 2);
  u16_t* H1   = (u16_t*)take(129UL * 65536 * 2);
  u16_t* H2   = (u16_t*)take(129UL * 65536 * 2);
  float* C2   = (float*)take(129UL * 65536 * 4);
  char* flagbase = ws + off;
  u32_t* FLC  = (u32_t*)take(128UL * 32 * 4);
  u32_t* FLA  = (u32_t*)take(128UL * 32 * 4);
  u32_t* FLB  = (u32_t*)take(128UL * 32 * 4);
  size_t flagbytes = (size_t)((ws + off) - flagbase);

  if (off > ws_size) return;  // workspace too small: fail loudly via wrong output

  hipMemsetAsync(flagbase, 0, flagbytes, stream);

  k_buildWC<<<1024, 256, 0, stream>>>(wih_f, whh_f, bih_f, bhh_f, WCf, bsf, 512);
  k_buildWC<<<1024, 256, 0, stream>>>(wih_b, whh_b, bih_b, bhh_b, WCb, bsb, 512);
  k_buildWC<<<4096, 256, 0, stream>>>(wih1, whh1, bih1, bhh1, WC1, bs1, 1024);
  k_buildWC<<<4096, 256, 0, stream>>>(wih2, whh2, bih2, bhh2, WC2, bs2, 1024);
  k_init<<<256, 256, 0, stream>>>(h0f, h0b, h01, h02, XIN, H1, H2);
  k_emb<<<2048, 256, 0, stream>>>(x, emb, Xemb);

  RP P;
  P.WCf = WCf; P.WCb = WCb; P.WC1 = WC1; P.WC2 = WC2;
  P.bsf = bsf; P.bsb = bsb; P.bs1 = bs1; P.bs2 = bs2;
  P.Xemb = Xemb; P.XIN = XIN; P.H1 = H1; P.H2 = H2; P.C2 = C2;
  P.FLC = FLC; P.FLA = FLA; P.FLB = FLB;
  P.c0f = c0f; P.c0b = c0b; P.c02 = c02;
  k_rnn<<<96, 512, 0, stream>>>(P);

  k_logits<<<250, 256, 0, stream>>>(H2 + 128UL * 65536, wlin, blin, (float*)d_out);
}

// Round 7
// 2939.006 us; speedup vs baseline: 1.9643x; 1.2194x over previous
//
#include <hip/hip_runtime.h>
#include <stdint.h>
#include <stddef.h>

typedef uint16_t u16_t;
typedef uint32_t u32_t;
typedef short s16x8 __attribute__((ext_vector_type(8)));
typedef uint16_t u16x4v __attribute__((ext_vector_type(4)));
typedef uint16_t u16x8v __attribute__((ext_vector_type(8)));
typedef float f32x4 __attribute__((ext_vector_type(4)));

#define DEV static __device__ __forceinline__

DEV u16_t f2bf(float f) {
  u32_t u = __float_as_uint(f);
  u += 0x7fffu + ((u >> 16) & 1u);   // round-to-nearest-even
  return (u16_t)(u >> 16);
}
DEV float sig_(float x) { return 1.f / (1.f + __expf(-x)); }
DEV float th_(float x) {
  x = fminf(15.f, fmaxf(-15.f, x));
  float e = __expf(2.f * x);
  return (e - 1.f) / (e + 1.f);
}

// =================== setup kernels ===================

__global__ void k_buildWC(const float* __restrict__ wih, const float* __restrict__ whh,
                          const float* __restrict__ bih, const float* __restrict__ bhh,
                          u16_t* __restrict__ WC, float* __restrict__ bs, int HH)
{
  const int K = HH * 2;
  const int nk8 = K >> 3;
  const long total = (long)HH * 4 * nk8;
  long idx = (long)blockIdx.x * blockDim.x + threadIdx.x;
  if (idx >= total) return;
  int p = (int)(idx / nk8);
  int k = (int)(idx - (long)p * nk8) << 3;
  int q = (p >> 4) & 3;
  int orig = q * HH + ((p >> 6) << 4) + (p & 15);
  const float* s = (k < HH) ? (wih + (size_t)orig * HH + k)
                            : (whh + (size_t)orig * HH + (k - HH));
  f32x4 a = *(const f32x4*)s;
  f32x4 b = *(const f32x4*)(s + 4);
  u16x8v o;
  o[0]=f2bf(a[0]); o[1]=f2bf(a[1]); o[2]=f2bf(a[2]); o[3]=f2bf(a[3]);
  o[4]=f2bf(b[0]); o[5]=f2bf(b[1]); o[6]=f2bf(b[2]); o[7]=f2bf(b[3]);
  *(u16x8v*)(WC + (size_t)p * K + k) = o;
  if (k == 0) bs[p] = bih[orig] + bhh[orig];
}

__global__ void k_init(const float* __restrict__ h0f, const float* __restrict__ h0b,
                       const float* __restrict__ h01, const float* __restrict__ h02,
                       u16_t* __restrict__ XIN0, u16_t* __restrict__ H1i, u16_t* __restrict__ H2i)
{
  int i = blockIdx.x * 256 + threadIdx.x;
  if (i >= 64 * 1024) return;
  int b = i >> 10, d = i & 1023;
  XIN0[i] = f2bf(d < 512 ? h0f[b * 512 + d] : h0b[b * 512 + (d - 512)]);
  H1i[i] = f2bf(h01[i]);
  H2i[i] = f2bf(h02[i]);
}

__global__ void k_emb(const int* __restrict__ x, const float* __restrict__ emb,
                      u16_t* __restrict__ Xemb)
{
  int idx = blockIdx.x * 256 + threadIdx.x;
  if (idx >= 524288) return;
  int sb = idx >> 6;
  int h0 = (idx & 63) << 3;
  int token = x[(sb >> 7) * 128 + (sb & 127)];
  u16x8v o = {0,0,0,0,0,0,0,0};
  if (token != 0) {
    const float* e = emb + (size_t)token * 512 + h0;
    f32x4 a = *(const f32x4*)e;
    f32x4 b = *(const f32x4*)(e + 4);
    o[0]=f2bf(a[0]); o[1]=f2bf(a[1]); o[2]=f2bf(a[2]); o[3]=f2bf(a[3]);
    o[4]=f2bf(b[0]); o[5]=f2bf(b[1]); o[6]=f2bf(b[2]); o[7]=f2bf(b[3]);
  }
  *(u16x8v*)(Xemb + (size_t)sb * 512 + h0) = o;
}

// =================== GEMM helpers ===================
// Chunk = [64 rows x 512 bf16] = 64 KB. 8 waves: each wave owns rows j*8+wave.
// LDS layout: row stride 1024 B, XOR swizzle byte^=((r&7)<<4) (G4).

// prefetch chunk into 8 regs/thread (16B per row slice)
DEV void pf8(s16x8 R[8], const u16_t* src, int ld, int wave, int lane)
{
#pragma unroll
  for (int j = 0; j < 8; ++j)
    R[j] = *(const s16x8*)(src + (size_t)(j * 8 + wave) * ld + lane * 8);
}

// write prefetched chunk into LDS (swizzled)
DEV void wr8(u16_t* sm, const s16x8 R[8], int wave, int lane)
{
#pragma unroll
  for (int j = 0; j < 8; ++j) {
    int r = j * 8 + wave;
    *(s16x8*)((char*)sm + r * 1024 + ((lane * 16) ^ ((r & 7) << 4))) = R[j];
  }
}

DEV s16x8 ld_afrag(const u16_t* smem, int m, int s, int lane)
{
  int r = m * 16 + (lane & 15);
  int off = (s * 64 + ((lane >> 4) << 4)) ^ ((r & 7) << 4);
  return *(const s16x8*)((const char*)smem + r * 1024 + off);
}

// 16 k-steps of MFMA over one staged chunk; weights streamed from L2
DEV void mfma16(f32x4 acc[4], const u16_t* sm, const u16_t* wptr, int lane)
{
#pragma unroll
  for (int s = 0; s < 16; ++s) {
    s16x8 bf = *(const s16x8*)(wptr + s * 32);
#pragma unroll
    for (int m = 0; m < 4; ++m) {
      s16x8 af = ld_afrag(sm, m, s, lane);
      acc[m] = __builtin_amdgcn_mfma_f32_16x16x32_bf16(af, bf, acc[m], 0, 0, 0);
    }
  }
}

// staging for k_logits (4 waves)
template<int W>
DEV void stage_chunkT(u16_t* smem, const u16_t* src, int ld, int wave, int lane)
{
#pragma unroll
  for (int j = 0; j < 64 / W; ++j) {
    int r = j * W + wave;
    s16x8 v = *(const s16x8*)(src + (size_t)r * ld + lane * 8);
    *(s16x8*)((char*)smem + r * 1024 + ((lane * 16) ^ ((r & 7) << 4))) = v;
  }
}

// wave's [64 x 16] tile -> smem exchange ex[wave][row][col]
DEV void acc_to_ex(float* ex, const f32x4 acc[4], int wave, int lane)
{
#pragma unroll
  for (int m = 0; m < 4; ++m)
#pragma unroll
    for (int r = 0; r < 4; ++r)
      ex[wave * 1024 + (m * 16 + ((lane >> 4) << 2) + r) * 16 + (lane & 15)] = acc[m][r];
}

// =================== fenceless flag sync ===================
DEV void ast8(void* p, const void* v)
{
  unsigned long long u; __builtin_memcpy(&u, v, 8);
  __hip_atomic_store((unsigned long long*)p, u, __ATOMIC_RELAXED, __HIP_MEMORY_SCOPE_AGENT);
}

DEV void wait_flags(u32_t* f, int n, int tid)
{
  if (tid < 64) {
    int guard = 0;
    for (;;) {
      u32_t v = (tid < n) ? __hip_atomic_load(f + tid, __ATOMIC_RELAXED, __HIP_MEMORY_SCOPE_AGENT) : 1u;
      if (__all(v != 0)) break;
      if (++guard > (1 << 22)) break;   // safety: never hang forever
      __builtin_amdgcn_s_sleep(1);      // throttle poll traffic
    }
  }
  __builtin_amdgcn_fence(__ATOMIC_ACQUIRE, "workgroup");  // compiler ordering only
  __syncthreads();
}

DEV void set_flag(u32_t* f, int tid)
{
  __syncthreads();   // s_waitcnt vmcnt(0) for every wave before s_barrier
  if (tid == 0) {
    __builtin_amdgcn_fence(__ATOMIC_RELEASE, "workgroup");  // compiler ordering only
    __hip_atomic_store(f, 1u, __ATOMIC_RELAXED, __HIP_MEMORY_SCOPE_AGENT);
  }
}

// =================== persistent RNN kernel ===================
// 96 WGs x 512 threads (8 waves): wg 0..31 cells (fwd 0..15, bwd 16..31),
// 32..63 layer1, 64..95 layer2. Each WG owns 128 gate cols = 32 h-dims.
// Async-stage split (T14): each chunk's global loads are issued into VGPRs
// one phase early (during prior MFMA / flag polling), then ds_write+barrier.
// Dependency graph (R6): L1 GEMM gated on FLA[u-1] only; c2 only gates the
// element-wise activation (single FLB flag).
struct RP {
  const u16_t *WCf, *WCb, *WC1, *WC2;
  const float *bsf, *bsb, *bs1, *bs2;
  const u16_t *Xemb;
  u16_t *XIN, *H1, *H2;     // [129][64][1024] bf16 slabs
  float *C2;                // [129][64][1024] f32 slabs
  u32_t *FLC, *FLA, *FLB;   // [128][32]
  const float *c0f, *c0b, *c02;
};

__global__ __launch_bounds__(512, 2) void k_rnn(RP P)
{
  __shared__ u16_t smem[32768];  // 64 KB: one chunk panel, reused as f32 exchange
  const int tid = threadIdx.x;
  const int wave = tid >> 6, lane = tid & 63;
  const int wg = blockIdx.x;
  const int b  = tid >> 3;          // batch 0..63
  const int d0 = (tid & 7) << 2;    // local h-dim base
  const int gl = d0 >> 4;
  const int jj = d0 & 15;
  const f32x4 vzero = {0.f, 0.f, 0.f, 0.f};
  s16x8 Ra[8], Rb[8];
  float* ex = (float*)smem;

  if (wg < 32) {
    // ---------------- fwd/bwd cells ----------------
    const bool cfwd = wg < 16;
    const int G = cfwd ? wg : wg - 16;
    const u16_t* WCc = cfwd ? P.WCf : P.WCb;
    const float* bsc = cfwd ? P.bsf : P.bsb;
    const float* c0 = cfwd ? P.c0f : P.c0b;
    float c_cell[4];
#pragma unroll
    for (int i = 0; i < 4; ++i) c_cell[i] = c0[b * 512 + G * 32 + d0 + i];
    const u16_t* wrow = WCc + (size_t)(G * 128 + wave * 16 + (lane & 15)) * 1024
                        + ((lane >> 4) << 3);

    for (int t = 0; t < 128; ++t) {
      f32x4 acc[4] = {vzero, vzero, vzero, vzero};
      int trow = cfwd ? t : 127 - t;
      // prefetch embedding chunk (always available)
      pf8(Ra, P.Xemb + (size_t)trow * 32768, 512, wave, lane);
      // own-direction h(t-1) flag (also guards smem reuse after prev act)
      if (t > 0) wait_flags(P.FLC + (t - 1) * 32 + (cfwd ? 0 : 16), 16, tid);
      else __syncthreads();
      wr8(smem, Ra, wave, lane);
      __syncthreads();
      pf8(Rb, P.XIN + (size_t)t * 65536 + (cfwd ? 0 : 512), 1024, wave, lane);
      mfma16(acc, smem, wrow, lane);
      __syncthreads();
      wr8(smem, Rb, wave, lane);
      __syncthreads();
      mfma16(acc, smem, wrow + 512, lane);
      __syncthreads();
      acc_to_ex(ex, acc, wave, lane);
      __syncthreads();
      u16x4v hv;
#pragma unroll
      for (int i = 0; i < 4; ++i) {
        int j = jj + i;
        float gq[4];
#pragma unroll
        for (int q = 0; q < 4; ++q)
          gq[q] = ex[(gl * 4 + q) * 1024 + b * 16 + j] + bsc[G * 128 + gl * 64 + q * 16 + j];
        float c = sig_(gq[1]) * c_cell[i] + sig_(gq[0]) * th_(gq[2]);
        c_cell[i] = c;
        hv[i] = f2bf(sig_(gq[3]) * th_(c));
      }
      ast8(P.XIN + (size_t)(t + 1) * 65536 + b * 1024 + (cfwd ? 0 : 512) + G * 32 + d0, &hv);
      set_flag(P.FLC + t * 32 + wg, tid);
    }
  } else if (wg < 64) {
    // ---------------- stacked layer 1 ----------------
    const int G = wg - 32;
    const u16_t* wrow = P.WC1 + (size_t)(G * 128 + wave * 16 + (lane & 15)) * 2048
                        + ((lane >> 4) << 3);

    for (int u = 0; u < 128; ++u) {
      f32x4 acc[4] = {vzero, vzero, vzero, vzero};
      // xin_u ready (cells run ahead); prefetch both halves during FLA wait
      wait_flags(P.FLC + u * 32, 32, tid);
      const u16_t* xin = P.XIN + (size_t)(u + 1) * 65536;
      pf8(Ra, xin, 1024, wave, lane);
      pf8(Rb, xin + 512, 1024, wave, lane);
      if (u > 0) wait_flags(P.FLA + (u - 1) * 32, 32, tid);
      const u16_t* h1p = P.H1 + (size_t)u * 65536;
      wr8(smem, Ra, wave, lane);
      __syncthreads();
      pf8(Ra, h1p, 1024, wave, lane);           // c2 issue under c0 MFMA
      mfma16(acc, smem, wrow, lane);
      __syncthreads();
      wr8(smem, Rb, wave, lane);
      __syncthreads();
      pf8(Rb, h1p + 512, 1024, wave, lane);     // c3 issue under c1 MFMA
      mfma16(acc, smem, wrow + 512, lane);
      __syncthreads();
      wr8(smem, Ra, wave, lane);
      __syncthreads();
      mfma16(acc, smem, wrow + 1024, lane);
      __syncthreads();
      wr8(smem, Rb, wave, lane);
      __syncthreads();
      mfma16(acc, smem, wrow + 1536, lane);
      __syncthreads();
      acc_to_ex(ex, acc, wave, lane);
      __syncthreads();
      // activation needs c2(u): single point-to-point flag from L2(u-1)
      if (u > 0) wait_flags(P.FLB + (u - 1) * 32 + G, 1, tid);
      const float* c2p = (u == 0) ? (P.c02 + b * 1024 + G * 32 + d0)
                                  : (P.C2 + (size_t)u * 65536 + b * 1024 + G * 32 + d0);
      u16x4v hv;
#pragma unroll
      for (int i = 0; i < 4; ++i) {
        int j = jj + i;
        float gq[4];
#pragma unroll
        for (int q = 0; q < 4; ++q)
          gq[q] = ex[(gl * 4 + q) * 1024 + b * 16 + j] + P.bs1[G * 128 + gl * 64 + q * 16 + j];
        // faithful quirk: layer-1 cell consumes c2; its own c is discarded
        float c1 = sig_(gq[1]) * c2p[i] + sig_(gq[0]) * th_(gq[2]);
        hv[i] = f2bf(sig_(gq[3]) * th_(c1));
      }
      ast8(P.H1 + (size_t)(u + 1) * 65536 + b * 1024 + G * 32 + d0, &hv);
      set_flag(P.FLA + u * 32 + G, tid);
    }
  } else {
    // ---------------- stacked layer 2 ----------------
    const int G = wg - 64;
    const u16_t* wrow = P.WC2 + (size_t)(G * 128 + wave * 16 + (lane & 15)) * 2048
                        + ((lane >> 4) << 3);
    float c2r[4];
#pragma unroll
    for (int i = 0; i < 4; ++i) c2r[i] = P.c02[b * 1024 + G * 32 + d0 + i];

    for (int u = 0; u < 128; ++u) {
      f32x4 acc[4] = {vzero, vzero, vzero, vzero};
      // early: h2(u-1), prefetched during FLB wait
      const u16_t* h2p = P.H2 + (size_t)u * 65536;
      if (u > 0) wait_flags(P.FLB + (u - 1) * 32, 32, tid);
      else __syncthreads();
      pf8(Ra, h2p, 1024, wave, lane);
      pf8(Rb, h2p + 512, 1024, wave, lane);
      wr8(smem, Ra, wave, lane);
      __syncthreads();
      mfma16(acc, smem, wrow + 1024, lane);
      __syncthreads();
      wr8(smem, Rb, wave, lane);
      __syncthreads();
      mfma16(acc, smem, wrow + 1536, lane);
      // critical hop: h1n. Split waits: lo half flags = G 0..15 = cols 0..511.
      const u16_t* h1n = P.H1 + (size_t)(u + 1) * 65536;
      wait_flags(P.FLA + u * 32, 16, tid);
      pf8(Ra, h1n, 1024, wave, lane);
      wait_flags(P.FLA + u * 32, 32, tid);
      pf8(Rb, h1n + 512, 1024, wave, lane);
      wr8(smem, Ra, wave, lane);
      __syncthreads();
      mfma16(acc, smem, wrow, lane);
      __syncthreads();
      wr8(smem, Rb, wave, lane);
      __syncthreads();
      mfma16(acc, smem, wrow + 512, lane);
      __syncthreads();
      acc_to_ex(ex, acc, wave, lane);
      __syncthreads();
      u16x4v hv; float c2o[4];
#pragma unroll
      for (int i = 0; i < 4; ++i) {
        int j = jj + i;
        float gq[4];
#pragma unroll
        for (int q = 0; q < 4; ++q)
          gq[q] = ex[(gl * 4 + q) * 1024 + b * 16 + j] + P.bs2[G * 128 + gl * 64 + q * 16 + j];
        float c2n = sig_(gq[1]) * c2r[i] + sig_(gq[0]) * th_(gq[2]);
        c2r[i] = c2n; c2o[i] = c2n;
        hv[i] = f2bf(sig_(gq[3]) * th_(c2n));
      }
      ast8(P.H2 + (size_t)(u + 1) * 65536 + b * 1024 + G * 32 + d0, &hv);
      float* c2dst = P.C2 + (size_t)(u + 1) * 65536 + b * 1024 + G * 32 + d0;
      ast8(c2dst, &c2o[0]);
      ast8(c2dst + 2, &c2o[2]);
      set_flag(P.FLB + u * 32 + G, tid);
    }
  }
}

// =================== final linear ===================
__global__ __launch_bounds__(256, 1) void k_logits(const u16_t* __restrict__ h2,
                                                   const float* __restrict__ wlin,
                                                   const float* __restrict__ blin,
                                                   float* __restrict__ out)
{
  __shared__ u16_t smem[32768];
  const int tid = threadIdx.x, wave = tid >> 6, lane = tid & 63;
  const int n0 = blockIdx.x * 128 + wave * 32;
  const f32x4 vzero = {0.f, 0.f, 0.f, 0.f};
  f32x4 acc[2][4];
#pragma unroll
  for (int nt = 0; nt < 2; ++nt)
#pragma unroll
    for (int m = 0; m < 4; ++m) acc[nt][m] = vzero;

  for (int c = 0; c < 2; ++c) {
    __syncthreads();
    stage_chunkT<4>(smem, h2 + c * 512, 1024, wave, lane);
    __syncthreads();
#pragma unroll
    for (int s = 0; s < 16; ++s) {
#pragma unroll
      for (int nt = 0; nt < 2; ++nt) {
        const float* wp = wlin + (size_t)(n0 + nt * 16 + (lane & 15)) * 1024
                          + c * 512 + s * 32 + ((lane >> 4) << 3);
        f32x4 w0 = *(const f32x4*)wp;
        f32x4 w1 = *(const f32x4*)(wp + 4);
        s16x8 bf;
        bf[0]=(short)f2bf(w0[0]); bf[1]=(short)f2bf(w0[1]);
        bf[2]=(short)f2bf(w0[2]); bf[3]=(short)f2bf(w0[3]);
        bf[4]=(short)f2bf(w1[0]); bf[5]=(short)f2bf(w1[1]);
        bf[6]=(short)f2bf(w1[2]); bf[7]=(short)f2bf(w1[3]);
#pragma unroll
        for (int m = 0; m < 4; ++m) {
          s16x8 af = ld_afrag(smem, m, s, lane);
          acc[nt][m] = __builtin_amdgcn_mfma_f32_16x16x32_bf16(af, bf, acc[nt][m], 0, 0, 0);
        }
      }
    }
  }
#pragma unroll
  for (int nt = 0; nt < 2; ++nt) {
    int col = n0 + nt * 16 + (lane & 15);
    float bl = blin[col];
#pragma unroll
    for (int m = 0; m < 4; ++m)
#pragma unroll
      for (int r = 0; r < 4; ++r) {
        int row = m * 16 + ((lane >> 4) << 2) + r;
        out[(size_t)row * 32000 + col] = acc[nt][m][r] + bl;
      }
  }
}

// =================== host ===================
extern "C" void kernel_launch(void* const* d_in, const int* in_sizes, int n_in,
                              void* d_out, int out_size, void* d_ws, size_t ws_size,
                              hipStream_t stream)
{
  (void)in_sizes; (void)n_in; (void)out_size;
  const int*   x     = (const int*)d_in[0];
  const float* emb   = (const float*)d_in[1];
  const float* h0f   = (const float*)d_in[2];
  const float* c0f   = (const float*)d_in[3];
  const float* h0b   = (const float*)d_in[4];
  const float* c0b   = (const float*)d_in[5];
  const float* h01   = (const float*)d_in[6];
  const float* h02   = (const float*)d_in[7];
  const float* c02   = (const float*)d_in[8];
  const float* wih_f = (const float*)d_in[9];
  const float* whh_f = (const float*)d_in[10];
  const float* bih_f = (const float*)d_in[11];
  const float* bhh_f = (const float*)d_in[12];
  const float* wih_b = (const float*)d_in[13];
  const float* whh_b = (const float*)d_in[14];
  const float* bih_b = (const float*)d_in[15];
  const float* bhh_b = (const float*)d_in[16];
  const float* wih1  = (const float*)d_in[17];
  const float* whh1  = (const float*)d_in[18];
  const float* bih1  = (const float*)d_in[19];
  const float* bhh1  = (const float*)d_in[20];
  const float* wih2  = (const float*)d_in[21];
  const float* whh2  = (const float*)d_in[22];
  const float* bih2  = (const float*)d_in[23];
  const float* bhh2  = (const float*)d_in[24];
  const float* wlin  = (const float*)d_in[25];
  const float* blin  = (const float*)d_in[26];

  char* ws = (char*)d_ws;
  size_t off = 0;
  auto take = [&](size_t n) { char* p = ws + off; off += (n + 255) & ~(size_t)255; return p; };

  u16_t* WCf  = (u16_t*)take(2048UL * 1024 * 2);
  u16_t* WCb  = (u16_t*)take(2048UL * 1024 * 2);
  u16_t* WC1  = (u16_t*)take(4096UL * 2048 * 2);
  u16_t* WC2  = (u16_t*)take(4096UL * 2048 * 2);
  float* bsf  = (float*)take(2048UL * 4);
  float* bsb  = (float*)take(2048UL * 4);
  float* bs1  = (float*)take(4096UL * 4);
  float* bs2  = (float*)take(4096UL * 4);
  u16_t* Xemb = (u16_t*)take(8192UL * 512 * 2);
  u16_t* XIN  = (u16_t*)take(129UL * 65536 * 2);
  u16_t* H1   = (u16_t*)take(129UL * 65536 * 2);
  u16_t* H2   = (u16_t*)take(129UL * 65536 * 2);
  float* C2   = (float*)take(129UL * 65536 * 4);
  char* flagbase = ws + off;
  u32_t* FLC  = (u32_t*)take(128UL * 32 * 4);
  u32_t* FLA  = (u32_t*)take(128UL * 32 * 4);
  u32_t* FLB  = (u32_t*)take(128UL * 32 * 4);
  size_t flagbytes = (size_t)((ws + off) - flagbase);

  if (off > ws_size) return;  // workspace too small: fail loudly via wrong output

  hipMemsetAsync(flagbase, 0, flagbytes, stream);

  k_buildWC<<<1024, 256, 0, stream>>>(wih_f, whh_f, bih_f, bhh_f, WCf, bsf, 512);
  k_buildWC<<<1024, 256, 0, stream>>>(wih_b, whh_b, bih_b, bhh_b, WCb, bsb, 512);
  k_buildWC<<<4096, 256, 0, stream>>>(wih1, whh1, bih1, bhh1, WC1, bs1, 1024);
  k_buildWC<<<4096, 256, 0, stream>>>(wih2, whh2, bih2, bhh2, WC2, bs2, 1024);
  k_init<<<256, 256, 0, stream>>>(h0f, h0b, h01, h02, XIN, H1, H2);
  k_emb<<<2048, 256, 0, stream>>>(x, emb, Xemb);

  RP P;
  P.WCf = WCf; P.WCb = WCb; P.WC1 = WC1; P.WC2 = WC2;
  P.bsf = bsf; P.bsb = bsb; P.bs1 = bs1; P.bs2 = bs2;
  P.Xemb = Xemb; P.XIN = XIN; P.H1 = H1; P.H2 = H2; P.C2 = C2;
  P.FLC = FLC; P.FLA = FLA; P.FLB = FLB;
  P.c0f = c0f; P.c0b = c0b; P.c02 = c02;
  k_rnn<<<96, 512, 0, stream>>>(P);

  k_logits<<<250, 256, 0, stream>>>(H2 + 128UL * 65536, wlin, blin, (float*)d_out);
}